// Round 4
// baseline (2265.224 us; speedup 1.0000x reference)
//
#include <hip/hip_runtime.h>
#include <cstddef>

#define N_NODES 50000
#define N_EDGES 800000

// ---------------------------------------------------------------------------
// agg init: agg = feat (so scatter adds on top of the self term (1+eps)*x, eps=0)
// ---------------------------------------------------------------------------
__global__ void copy_f4_kernel(const float4* __restrict__ in, float4* __restrict__ out, int n4) {
    int stride = gridDim.x * blockDim.x;
    for (int i = blockIdx.x * blockDim.x + threadIdx.x; i < n4; i += stride)
        out[i] = in[i];
}

// ---------------------------------------------------------------------------
// scatter-add: agg[dst[e]][:] += feat[src[e]][:].
// One thread per (edge, 4 features): float4 gather + 4 atomicAdds.
// D/4 consecutive threads share an edge -> uniform src/dst loads, coalesced
// 16B row gather, dense consecutive atomic addresses.
// NOTE: edge indices arrive as int32 (harness converts integer inputs).
// ---------------------------------------------------------------------------
template<int LOGD4>   // log2(D/4)
__global__ void scatter_add_kernel(const float* __restrict__ feat,
                                   const int* __restrict__ src,
                                   const int* __restrict__ dst,
                                   float* __restrict__ agg, int total) {
    const int D = 4 << LOGD4;
    int stride = gridDim.x * blockDim.x;
    for (int i = blockIdx.x * blockDim.x + threadIdx.x; i < total; i += stride) {
        int e  = i >> LOGD4;
        int t4 = (i & ((1 << LOGD4) - 1)) << 2;
        int s = src[e];
        int d = dst[e];
        float4 v = *(const float4*)(feat + (size_t)s * D + t4);
        float* ap = agg + (size_t)d * D + t4;
        atomicAdd(ap + 0, v.x);
        atomicAdd(ap + 1, v.y);
        atomicAdd(ap + 2, v.z);
        atomicAdd(ap + 3, v.w);
    }
}

// ---------------------------------------------------------------------------
// fp32 GEMM, C[M,N] = act(A[M,K] @ W[K,N] + bias), 64x64 tile, 256 thr, 4x4/thr
// LDS rows padded to 68 floats (272B = 17*16B): float4-aligned, conflict-free.
// ---------------------------------------------------------------------------
__global__ __launch_bounds__(256)
void gemm_bias_relu(const float* __restrict__ A, const float* __restrict__ W,
                    const float* __restrict__ bias, float* __restrict__ C,
                    int M, int K, int N, int do_relu) {
    __shared__ __align__(16) float As[16][68];   // As[k][m] (A transposed in LDS)
    __shared__ __align__(16) float Bs[16][68];   // Bs[k][n]

    const int tid = threadIdx.x;
    const int tx  = tid & 15;        // col group
    const int ty  = tid >> 4;        // row group
    const int row0 = blockIdx.y * 64;
    const int col0 = blockIdx.x * 64;

    float acc[4][4];
#pragma unroll
    for (int i = 0; i < 4; ++i)
#pragma unroll
        for (int j = 0; j < 4; ++j) acc[i][j] = 0.f;

    // A-tile load mapping: thread -> (row am, 4 consecutive k at ak)
    const int am = tid >> 2;
    const int ak = (tid & 3) << 2;
    int arow = row0 + am;
    if (arow >= M) arow = M - 1;     // clamp (stores are guarded)
    // B-tile load mapping: thread -> (k row bk, 4 consecutive cols at bn)
    const int bk = tid >> 4;
    const int bn = (tid & 15) << 2;

    for (int k0 = 0; k0 < K; k0 += 16) {
        float4 av = *(const float4*)(A + (size_t)arow * K + k0 + ak);
        float4 bv = *(const float4*)(W + (size_t)(k0 + bk) * N + col0 + bn);
        As[ak + 0][am] = av.x;
        As[ak + 1][am] = av.y;
        As[ak + 2][am] = av.z;
        As[ak + 3][am] = av.w;
        *(float4*)(&Bs[bk][bn]) = bv;
        __syncthreads();
#pragma unroll
        for (int kk = 0; kk < 16; ++kk) {
            float4 a4 = *(const float4*)(&As[kk][ty << 2]);
            float4 b4 = *(const float4*)(&Bs[kk][tx << 2]);
            float a[4] = {a4.x, a4.y, a4.z, a4.w};
            float b[4] = {b4.x, b4.y, b4.z, b4.w};
#pragma unroll
            for (int i = 0; i < 4; ++i)
#pragma unroll
                for (int j = 0; j < 4; ++j)
                    acc[i][j] = fmaf(a[i], b[j], acc[i][j]);
        }
        __syncthreads();
    }

    float4 bb = *(const float4*)(bias + col0 + (tx << 2));
    float bias4[4] = {bb.x, bb.y, bb.z, bb.w};
#pragma unroll
    for (int i = 0; i < 4; ++i) {
        int row = row0 + (ty << 2) + i;
        if (row < M) {
            float4 v;
            float* vp = &v.x;
#pragma unroll
            for (int j = 0; j < 4; ++j) {
                float t = acc[i][j] + bias4[j];
                if (do_relu) t = fmaxf(t, 0.f);
                vp[j] = t;
            }
            *(float4*)(C + (size_t)row * N + col0 + (tx << 2)) = v;
        }
    }
}

// ---------------------------------------------------------------------------
// final projection: out[r] = dot(h4[r,:128], w5) + b5, one wave per row
// ---------------------------------------------------------------------------
__global__ void out_proj_kernel(const float* __restrict__ h, const float* __restrict__ w,
                                const float* __restrict__ b, float* __restrict__ out, int M) {
    int lane = threadIdx.x & 63;
    int wave = threadIdx.x >> 6;
    int wpb  = blockDim.x >> 6;
    float w0 = w[lane], w1 = w[64 + lane];
    float bb = b[0];
    for (int row = blockIdx.x * wpb + wave; row < M; row += gridDim.x * wpb) {
        const float* hr = h + (size_t)row * 128;
        float s = hr[lane] * w0 + hr[64 + lane] * w1;
#pragma unroll
        for (int off = 32; off > 0; off >>= 1) s += __shfl_xor(s, off, 64);
        if (lane == 0) out[row] = s + bb;
    }
}

// ---------------------------------------------------------------------------
extern "C" void kernel_launch(void* const* d_in, const int* in_sizes, int n_in,
                              void* d_out, int out_size, void* d_ws, size_t ws_size,
                              hipStream_t stream) {
    const float* x      = (const float*)d_in[0];
    const int*   edge   = (const int*)d_in[1];     // int32 on device (harness converts)
    const float* W1 = (const float*)d_in[2];
    const float* b1 = (const float*)d_in[3];
    const float* W2 = (const float*)d_in[4];
    const float* b2 = (const float*)d_in[5];
    const float* W3 = (const float*)d_in[6];
    const float* b3 = (const float*)d_in[7];
    const float* W4 = (const float*)d_in[8];
    const float* b4 = (const float*)d_in[9];
    const float* W5 = (const float*)d_in[10];
    const float* b5 = (const float*)d_in[11];
    float* out = (float*)d_out;

    const int N = N_NODES, E = N_EDGES;
    const int* src = edge;
    const int* dst = edge + E;

    // workspace layout (floats), lifetimes audited; peak = N*384*4B = 76.8 MB
    //   phase        live regions
    //   scatter1     agg1 [128N,192N)
    //   gemm1        agg1 -> h1 [0,128N)
    //   scatter2     h1, agg2 [256N,384N)
    //   gemm2        agg2 -> h2 [0,256N)        (h1 dead, overwritten)
    //   gemm3        h2   -> h3 [256N,384N)     (agg2 dead)
    //   gemm4        h3   -> h4 [0,128N)        (h2 dead)
    //   out_proj     h4
    float* ws   = (float*)d_ws;
    float* h1   = ws;                    // 128N
    float* agg1 = ws + (size_t)N * 128;  // 64N
    float* agg2 = ws + (size_t)N * 256;  // 128N
    float* h2   = ws;                    // 256N (over dead h1)
    float* h3   = ws + (size_t)N * 256;  // 128N (over dead agg2)
    float* h4   = ws;                    // 128N (over dead h2)

    dim3 blk(256);

    // layer 1: agg1 = x + scatter(x); h1 = relu(agg1 @ W1 + b1)
    copy_f4_kernel<<<2048, blk, 0, stream>>>((const float4*)x, (float4*)agg1, N * 64 / 4);
    scatter_add_kernel<4><<<8192, blk, 0, stream>>>(x, src, dst, agg1, E * 16);
    dim3 g1(128 / 64, (N + 63) / 64);
    gemm_bias_relu<<<g1, blk, 0, stream>>>(agg1, W1, b1, h1, N, 64, 128, 1);

    // layer 2: agg2 = h1 + scatter(h1); h2 = relu(agg2 @ W2 + b2)
    copy_f4_kernel<<<2048, blk, 0, stream>>>((const float4*)h1, (float4*)agg2, N * 128 / 4);
    scatter_add_kernel<5><<<8192, blk, 0, stream>>>(h1, src, dst, agg2, E * 32);
    dim3 g2(256 / 64, (N + 63) / 64);
    gemm_bias_relu<<<g2, blk, 0, stream>>>(agg2, W2, b2, h2, N, 128, 256, 1);

    // dense head
    dim3 g3(128 / 64, (N + 63) / 64);
    gemm_bias_relu<<<g3, blk, 0, stream>>>(h2, W3, b3, h3, N, 256, 128, 1);
    gemm_bias_relu<<<g3, blk, 0, stream>>>(h3, W4, b4, h4, N, 128, 128, 1);
    out_proj_kernel<<<2048, blk, 0, stream>>>(h4, W5, b5, out, N);
}

// Round 5
// 501.553 us; speedup vs baseline: 4.5164x; 4.5164x over previous
//
#include <hip/hip_runtime.h>
#include <cstddef>

#define N_NODES 50000
#define N_EDGES 800000

// ---------------------------------------------------------------------------
// CSR build: deg -> exclusive scan -> slot fill.  Indices arrive as int32.
// ---------------------------------------------------------------------------
__global__ void zero_int_kernel(int* __restrict__ p, int n) {
    int stride = gridDim.x * blockDim.x;
    for (int i = blockIdx.x * blockDim.x + threadIdx.x; i < n; i += stride) p[i] = 0;
}

__global__ void hist_kernel(const int* __restrict__ dst, int* __restrict__ deg, int E) {
    int stride = gridDim.x * blockDim.x;
    for (int e = blockIdx.x * blockDim.x + threadIdx.x; e < E; e += stride)
        atomicAdd(&deg[dst[e]], 1);
}

// single-block exclusive scan over n=50000 ints, 1024 threads, wave-shfl based.
// Writes row_ptr[0..n] and cursor[0..n-1] (cursor may alias deg: each element is
// read by the same thread that later overwrites it).
__global__ __launch_bounds__(1024)
void scan_kernel(const int* __restrict__ deg, int* __restrict__ row_ptr,
                 int* __restrict__ cursor, int n) {
    __shared__ int wsum[16];
    __shared__ int carry_s;
    const int lane = threadIdx.x & 63;
    const int wid  = threadIdx.x >> 6;
    if (threadIdx.x == 0) carry_s = 0;
    __syncthreads();
    for (int base = 0; base < n; base += 1024) {
        int i = base + threadIdx.x;
        int v = (i < n) ? deg[i] : 0;
        int s = v;                       // inclusive wave scan
#pragma unroll
        for (int off = 1; off < 64; off <<= 1) {
            int t = __shfl_up(s, off, 64);
            if (lane >= off) s += t;
        }
        if (lane == 63) wsum[wid] = s;
        __syncthreads();
        if (wid == 0) {                  // scan the 16 wave sums
            int ws = (lane < 16) ? wsum[lane] : 0;
#pragma unroll
            for (int off = 1; off < 16; off <<= 1) {
                int t = __shfl_up(ws, off, 64);
                if (lane >= off) ws += t;
            }
            if (lane < 16) wsum[lane] = ws;
        }
        __syncthreads();
        int carry = carry_s;
        int wave_off = wid ? wsum[wid - 1] : 0;
        int excl = carry + wave_off + s - v;
        if (i < n) { row_ptr[i] = excl; cursor[i] = excl; }
        __syncthreads();
        if (threadIdx.x == 1023) carry_s = carry + wsum[15];
        __syncthreads();
    }
    if (threadIdx.x == 0) row_ptr[n] = carry_s;
}

__global__ void fill_kernel(const int* __restrict__ src, const int* __restrict__ dst,
                            int* __restrict__ cursor, int* __restrict__ col, int E) {
    int stride = gridDim.x * blockDim.x;
    for (int e = blockIdx.x * blockDim.x + threadIdx.x; e < E; e += stride) {
        int p = atomicAdd(&cursor[dst[e]], 1);
        col[p] = src[e];
    }
}

// ---------------------------------------------------------------------------
// GIN aggregation: agg[v] = feat[v] + sum_{u in in-nbrs(v)} feat[u].
// One wave per node; lane holds D/64 floats. Edge ids batched 64-wide and
// broadcast via shfl; row reads are coalesced (256B/512B segments).
// ---------------------------------------------------------------------------
template<int D>
__global__ __launch_bounds__(256)
void gin_aggregate(const float* __restrict__ feat, const int* __restrict__ row_ptr,
                   const int* __restrict__ col, float* __restrict__ agg, int n) {
    int gwid = (blockIdx.x * blockDim.x + threadIdx.x) >> 6;
    int lane = threadIdx.x & 63;
    int nwav = (gridDim.x * blockDim.x) >> 6;
    for (int v = gwid; v < n; v += nwav) {
        float2 acc;
        if constexpr (D == 128) acc = ((const float2*)(feat + (size_t)v * D))[lane];
        else { acc.x = feat[(size_t)v * D + lane]; acc.y = 0.f; }
        int beg = row_ptr[v], end = row_ptr[v + 1];
        for (int j = beg; j < end; j += 64) {
            int batch = end - j; if (batch > 64) batch = 64;
            int e = (lane < batch) ? col[j + lane] : 0;
            for (int k = 0; k < batch; ++k) {
                int s = __shfl(e, k, 64);
                if constexpr (D == 128) {
                    float2 r = ((const float2*)(feat + (size_t)s * D))[lane];
                    acc.x += r.x; acc.y += r.y;
                } else {
                    acc.x += feat[(size_t)s * D + lane];
                }
            }
        }
        if constexpr (D == 128) ((float2*)(agg + (size_t)v * D))[lane] = acc;
        else agg[(size_t)v * D + lane] = acc.x;
    }
}

// ---------------------------------------------------------------------------
// fp32 GEMM, C[M,N] = act(A[M,K] @ W[K,N] + bias), 64x64 tile, 256 thr, 4x4/thr
// ---------------------------------------------------------------------------
__global__ __launch_bounds__(256)
void gemm_bias_relu(const float* __restrict__ A, const float* __restrict__ W,
                    const float* __restrict__ bias, float* __restrict__ C,
                    int M, int K, int N, int do_relu) {
    __shared__ __align__(16) float As[16][68];
    __shared__ __align__(16) float Bs[16][68];

    const int tid = threadIdx.x;
    const int tx  = tid & 15;
    const int ty  = tid >> 4;
    const int row0 = blockIdx.y * 64;
    const int col0 = blockIdx.x * 64;

    float acc[4][4];
#pragma unroll
    for (int i = 0; i < 4; ++i)
#pragma unroll
        for (int j = 0; j < 4; ++j) acc[i][j] = 0.f;

    const int am = tid >> 2;
    const int ak = (tid & 3) << 2;
    int arow = row0 + am;
    if (arow >= M) arow = M - 1;
    const int bk = tid >> 4;
    const int bn = (tid & 15) << 2;

    for (int k0 = 0; k0 < K; k0 += 16) {
        float4 av = *(const float4*)(A + (size_t)arow * K + k0 + ak);
        float4 bv = *(const float4*)(W + (size_t)(k0 + bk) * N + col0 + bn);
        As[ak + 0][am] = av.x;
        As[ak + 1][am] = av.y;
        As[ak + 2][am] = av.z;
        As[ak + 3][am] = av.w;
        *(float4*)(&Bs[bk][bn]) = bv;
        __syncthreads();
#pragma unroll
        for (int kk = 0; kk < 16; ++kk) {
            float4 a4 = *(const float4*)(&As[kk][ty << 2]);
            float4 b4 = *(const float4*)(&Bs[kk][tx << 2]);
            float a[4] = {a4.x, a4.y, a4.z, a4.w};
            float b[4] = {b4.x, b4.y, b4.z, b4.w};
#pragma unroll
            for (int i = 0; i < 4; ++i)
#pragma unroll
                for (int j = 0; j < 4; ++j)
                    acc[i][j] = fmaf(a[i], b[j], acc[i][j]);
        }
        __syncthreads();
    }

    float4 bb = *(const float4*)(bias + col0 + (tx << 2));
    float bias4[4] = {bb.x, bb.y, bb.z, bb.w};
#pragma unroll
    for (int i = 0; i < 4; ++i) {
        int row = row0 + (ty << 2) + i;
        if (row < M) {
            float4 v;
            float* vp = &v.x;
#pragma unroll
            for (int j = 0; j < 4; ++j) {
                float t = acc[i][j] + bias4[j];
                if (do_relu) t = fmaxf(t, 0.f);
                vp[j] = t;
            }
            *(float4*)(C + (size_t)row * N + col0 + (tx << 2)) = v;
        }
    }
}

// ---------------------------------------------------------------------------
// final projection: out[r] = dot(h4[r,:128], w5) + b5, one wave per row
// ---------------------------------------------------------------------------
__global__ void out_proj_kernel(const float* __restrict__ h, const float* __restrict__ w,
                                const float* __restrict__ b, float* __restrict__ out, int M) {
    int lane = threadIdx.x & 63;
    int wave = threadIdx.x >> 6;
    int wpb  = blockDim.x >> 6;
    float w0 = w[lane], w1 = w[64 + lane];
    float bb = b[0];
    for (int row = blockIdx.x * wpb + wave; row < M; row += gridDim.x * wpb) {
        const float* hr = h + (size_t)row * 128;
        float s = hr[lane] * w0 + hr[64 + lane] * w1;
#pragma unroll
        for (int off = 32; off > 0; off >>= 1) s += __shfl_xor(s, off, 64);
        if (lane == 0) out[row] = s + bb;
    }
}

// ---------------------------------------------------------------------------
extern "C" void kernel_launch(void* const* d_in, const int* in_sizes, int n_in,
                              void* d_out, int out_size, void* d_ws, size_t ws_size,
                              hipStream_t stream) {
    const float* x    = (const float*)d_in[0];
    const int*   edge = (const int*)d_in[1];     // int32 on device (harness converts)
    const float* W1 = (const float*)d_in[2];
    const float* b1 = (const float*)d_in[3];
    const float* W2 = (const float*)d_in[4];
    const float* b2 = (const float*)d_in[5];
    const float* W3 = (const float*)d_in[6];
    const float* b3 = (const float*)d_in[7];
    const float* W4 = (const float*)d_in[8];
    const float* b4 = (const float*)d_in[9];
    const float* W5 = (const float*)d_in[10];
    const float* b5 = (const float*)d_in[11];
    float* out = (float*)d_out;

    const int N = N_NODES, E = N_EDGES;
    const int* src = edge;
    const int* dst = edge + E;

    // float workspace (lifetimes audited; peak 384N floats = 76.8 MB):
    //   agg1 [128N,192N) -> h1 [0,128N) -> agg2 [256N,384N) -> h2 [0,256N)
    //   -> h3 [256N,384N) -> h4 [0,128N)
    float* ws   = (float*)d_ws;
    float* h1   = ws;
    float* agg1 = ws + (size_t)N * 128;
    float* agg2 = ws + (size_t)N * 256;
    float* h2   = ws;
    float* h3   = ws + (size_t)N * 256;
    float* h4   = ws;

    // int workspace after the float region (~3.6 MB)
    int* ibase   = (int*)(ws + (size_t)N * 384);
    int* deg     = ibase;              // N   (reused as cursor)
    int* row_ptr = ibase + N;          // N+1
    int* colidx  = ibase + 2 * N + 1;  // E

    dim3 blk(256);

    // ---- CSR build (once per call, shared by both GIN layers) ----
    zero_int_kernel<<<64, blk, 0, stream>>>(deg, N);
    hist_kernel<<<2048, blk, 0, stream>>>(dst, deg, E);
    scan_kernel<<<1, 1024, 0, stream>>>(deg, row_ptr, /*cursor=*/deg, N);
    fill_kernel<<<2048, blk, 0, stream>>>(src, dst, /*cursor=*/deg, colidx, E);

    // ---- layer 1: agg1 = x + gather-sum(x); h1 = relu(agg1 @ W1 + b1) ----
    gin_aggregate<64><<<3125, blk, 0, stream>>>(x, row_ptr, colidx, agg1, N);
    dim3 g1(128 / 64, (N + 63) / 64);
    gemm_bias_relu<<<g1, blk, 0, stream>>>(agg1, W1, b1, h1, N, 64, 128, 1);

    // ---- layer 2: agg2 = h1 + gather-sum(h1); h2 = relu(agg2 @ W2 + b2) ----
    gin_aggregate<128><<<3125, blk, 0, stream>>>(h1, row_ptr, colidx, agg2, N);
    dim3 g2(256 / 64, (N + 63) / 64);
    gemm_bias_relu<<<g2, blk, 0, stream>>>(agg2, W2, b2, h2, N, 128, 256, 1);

    // ---- dense head ----
    dim3 g3(128 / 64, (N + 63) / 64);
    gemm_bias_relu<<<g3, blk, 0, stream>>>(h2, W3, b3, h3, N, 256, 128, 1);
    gemm_bias_relu<<<g3, blk, 0, stream>>>(h3, W4, b4, h4, N, 128, 128, 1);
    out_proj_kernel<<<2048, blk, 0, stream>>>(h4, W5, b5, out, N);
}

// Round 8
// 460.921 us; speedup vs baseline: 4.9146x; 1.0882x over previous
//
#include <hip/hip_runtime.h>
#include <cstddef>

#define N_NODES 50000
#define N_EDGES 800000

// ---------------------------------------------------------------------------
// CSR build: deg -> multi-block exclusive scan -> slot fill. Indices int32.
// ---------------------------------------------------------------------------
__global__ void zero_int_kernel(int* __restrict__ p, int n) {
    int stride = gridDim.x * blockDim.x;
    for (int i = blockIdx.x * blockDim.x + threadIdx.x; i < n; i += stride) p[i] = 0;
}

__global__ void hist_kernel(const int* __restrict__ dst, int* __restrict__ deg, int E) {
    int stride = gridDim.x * blockDim.x;
    for (int e = blockIdx.x * blockDim.x + threadIdx.x; e < E; e += stride)
        atomicAdd(&deg[dst[e]], 1);
}

// per-1024-block local exclusive scan; block totals to part[]
__global__ __launch_bounds__(1024)
void scan_blocks(const int* __restrict__ deg, int* __restrict__ loc,
                 int* __restrict__ part, int n) {
    __shared__ int wsum[16];
    const int lane = threadIdx.x & 63;
    const int wid  = threadIdx.x >> 6;
    int i = blockIdx.x * 1024 + threadIdx.x;
    int v = (i < n) ? deg[i] : 0;
    int s = v;
#pragma unroll
    for (int off = 1; off < 64; off <<= 1) {
        int t = __shfl_up(s, off, 64);
        if (lane >= off) s += t;
    }
    if (lane == 63) wsum[wid] = s;
    __syncthreads();
    if (wid == 0) {
        int ws = (lane < 16) ? wsum[lane] : 0;
#pragma unroll
        for (int off = 1; off < 16; off <<= 1) {
            int t = __shfl_up(ws, off, 64);
            if (lane >= off) ws += t;
        }
        if (lane < 16) wsum[lane] = ws;
    }
    __syncthreads();
    int excl = (wid ? wsum[wid - 1] : 0) + s - v;
    if (i < n) loc[i] = excl;
    if (threadIdx.x == 1023) part[blockIdx.x] = wsum[15];
}

// scan <=63 block partials with one wave; part becomes exclusive, part[nb]=total
__global__ void scan_tops(int* __restrict__ part, int nb) {
    int lane = threadIdx.x;
    int v = (lane < nb) ? part[lane] : 0;
    int s = v;
#pragma unroll
    for (int off = 1; off < 64; off <<= 1) {
        int t = __shfl_up(s, off, 64);
        if (lane >= off) s += t;
    }
    if (lane < nb) part[lane] = s - v;
    if (lane == nb - 1) part[nb] = s;
}

__global__ __launch_bounds__(1024)
void scan_add(const int* __restrict__ loc, const int* __restrict__ part,
              int* __restrict__ row_ptr, int* __restrict__ cursor, int n, int nb) {
    int i = blockIdx.x * 1024 + threadIdx.x;
    if (i < n) {
        int r = loc[i] + part[i >> 10];
        row_ptr[i] = r;
        cursor[i]  = r;
    }
    if (i == 0) row_ptr[n] = part[nb];
}

__global__ void fill_kernel(const int* __restrict__ src, const int* __restrict__ dst,
                            int* __restrict__ cursor, int* __restrict__ col, int E) {
    int stride = gridDim.x * blockDim.x;
    for (int e = blockIdx.x * blockDim.x + threadIdx.x; e < E; e += stride) {
        int p = atomicAdd(&cursor[dst[e]], 1);
        col[p] = src[e];
    }
}

// ---------------------------------------------------------------------------
// GIN aggregation: agg[v] = feat[v] + sum_{u in in-nbrs(v)} feat[u].
// One wave per node; ~5.7 TB/s delivered (measured r5) — near memory floor.
// ---------------------------------------------------------------------------
template<int D>
__global__ __launch_bounds__(256)
void gin_aggregate(const float* __restrict__ feat, const int* __restrict__ row_ptr,
                   const int* __restrict__ col, float* __restrict__ agg, int n) {
    int gwid = (blockIdx.x * blockDim.x + threadIdx.x) >> 6;
    int lane = threadIdx.x & 63;
    int nwav = (gridDim.x * blockDim.x) >> 6;
    for (int v = gwid; v < n; v += nwav) {
        float2 acc;
        if constexpr (D == 128) acc = ((const float2*)(feat + (size_t)v * D))[lane];
        else { acc.x = feat[(size_t)v * D + lane]; acc.y = 0.f; }
        int beg = row_ptr[v], end = row_ptr[v + 1];
        for (int j = beg; j < end; j += 64) {
            int batch = end - j; if (batch > 64) batch = 64;
            int e = (lane < batch) ? col[j + lane] : 0;
            for (int k = 0; k < batch; ++k) {
                int s = __shfl(e, k, 64);
                if constexpr (D == 128) {
                    float2 r = ((const float2*)(feat + (size_t)s * D))[lane];
                    acc.x += r.x; acc.y += r.y;
                } else {
                    acc.x += feat[(size_t)s * D + lane];
                }
            }
        }
        if constexpr (D == 128) ((float2*)(agg + (size_t)v * D))[lane] = acc;
        else agg[(size_t)v * D + lane] = acc.x;
    }
}

// ---------------------------------------------------------------------------
// fp32 GEMM, C = relu(A[M,K] @ W[K,N] + bias). 128xBN tile, 256 thr,
// 8xTN per thread (TN=BN/16). Frag cols/rows split {g*4, 64+g*4} so wave LDS
// reads are <=2-way bank-aliased (free). K-accumulation order = naive order.
// ---------------------------------------------------------------------------
template<int BN>   // 64 or 128
__global__ __launch_bounds__(256)
void gemm_bias_relu(const float* __restrict__ A, const float* __restrict__ W,
                    const float* __restrict__ bias, float* __restrict__ C,
                    int M, int K, int N, int do_relu) {
    constexpr int TN = BN / 16;               // cols per thread (4 or 8)
    __shared__ __align__(16) float As[16][132];
    __shared__ __align__(16) float Bs[16][BN + 4];

    const int tid = threadIdx.x;
    const int tx  = tid & 15;
    const int ty  = tid >> 4;
    const int row0 = blockIdx.y * 128;
    const int col0 = blockIdx.x * BN;

    float acc[8][TN];
#pragma unroll
    for (int i = 0; i < 8; ++i)
#pragma unroll
        for (int j = 0; j < TN; ++j) acc[i][j] = 0.f;

    constexpr int BF4   = BN / 4;             // float4 per B row (16 or 32)
    constexpr int BLOAD = 16 * BF4 / 256;     // B float4 loads per thread (1 or 2)

    for (int k0 = 0; k0 < K; k0 += 16) {
        // A tile: 128 rows x 16 k -> As[k][row]; 2 float4 per thread
#pragma unroll
        for (int h = 0; h < 2; ++h) {
            int idx = tid + h * 256;
            int ar  = idx >> 2;
            int akc = (idx & 3) << 2;
            int arow = row0 + ar; if (arow >= M) arow = M - 1;
            float4 av = *(const float4*)(A + (size_t)arow * K + k0 + akc);
            As[akc + 0][ar] = av.x;
            As[akc + 1][ar] = av.y;
            As[akc + 2][ar] = av.z;
            As[akc + 3][ar] = av.w;
        }
        // B tile: 16 k x BN cols -> Bs[k][col]
#pragma unroll
        for (int h = 0; h < BLOAD; ++h) {
            int idx = tid + h * 256;
            int kr  = idx / BF4;
            int cc  = (idx % BF4) << 2;
            float4 bv = *(const float4*)(W + (size_t)(k0 + kr) * N + col0 + cc);
            *(float4*)(&Bs[kr][cc]) = bv;
        }
        __syncthreads();
#pragma unroll
        for (int kk = 0; kk < 16; ++kk) {
            float a[8];
            float4 a0 = *(const float4*)(&As[kk][ty << 2]);
            float4 a1 = *(const float4*)(&As[kk][64 + (ty << 2)]);
            a[0]=a0.x; a[1]=a0.y; a[2]=a0.z; a[3]=a0.w;
            a[4]=a1.x; a[5]=a1.y; a[6]=a1.z; a[7]=a1.w;
            float b[TN];
            float4 b0 = *(const float4*)(&Bs[kk][tx << 2]);
            b[0]=b0.x; b[1]=b0.y; b[2]=b0.z; b[3]=b0.w;
            if constexpr (TN == 8) {
                float4 b1 = *(const float4*)(&Bs[kk][64 + (tx << 2)]);
                b[4]=b1.x; b[5]=b1.y; b[6]=b1.z; b[7]=b1.w;
            }
#pragma unroll
            for (int i = 0; i < 8; ++i)
#pragma unroll
                for (int j = 0; j < TN; ++j)
                    acc[i][j] = fmaf(a[i], b[j], acc[i][j]);
        }
        __syncthreads();
    }

    // epilogue: bias + relu + guarded float4 stores
    float bs[TN];
    {
        float4 bb0 = *(const float4*)(bias + col0 + (tx << 2));
        bs[0]=bb0.x; bs[1]=bb0.y; bs[2]=bb0.z; bs[3]=bb0.w;
        if constexpr (TN == 8) {
            float4 bb1 = *(const float4*)(bias + col0 + 64 + (tx << 2));
            bs[4]=bb1.x; bs[5]=bb1.y; bs[6]=bb1.z; bs[7]=bb1.w;
        }
    }
#pragma unroll
    for (int i = 0; i < 8; ++i) {
        int row = row0 + ((i < 4) ? (ty << 2) + i : 64 + (ty << 2) + (i - 4));
        if (row < M) {
#pragma unroll
            for (int g = 0; g < TN / 4; ++g) {
                float4 v;
                float* vp = &v.x;
#pragma unroll
                for (int j = 0; j < 4; ++j) {
                    float t = acc[i][g * 4 + j] + bs[g * 4 + j];
                    if (do_relu) t = fmaxf(t, 0.f);
                    vp[j] = t;
                }
                *(float4*)(C + (size_t)row * N + col0 + g * 64 + (tx << 2)) = v;
            }
        }
    }
}

// ---------------------------------------------------------------------------
// final projection: out[r] = dot(h4[r,:128], w5) + b5, one wave per row
// ---------------------------------------------------------------------------
__global__ void out_proj_kernel(const float* __restrict__ h, const float* __restrict__ w,
                                const float* __restrict__ b, float* __restrict__ out, int M) {
    int lane = threadIdx.x & 63;
    int wave = threadIdx.x >> 6;
    int wpb  = blockDim.x >> 6;
    float w0 = w[lane], w1 = w[64 + lane];
    float bb = b[0];
    for (int row = blockIdx.x * wpb + wave; row < M; row += gridDim.x * wpb) {
        const float* hr = h + (size_t)row * 128;
        float s = hr[lane] * w0 + hr[64 + lane] * w1;
#pragma unroll
        for (int off = 32; off > 0; off >>= 1) s += __shfl_xor(s, off, 64);
        if (lane == 0) out[row] = s + bb;
    }
}

// ---------------------------------------------------------------------------
extern "C" void kernel_launch(void* const* d_in, const int* in_sizes, int n_in,
                              void* d_out, int out_size, void* d_ws, size_t ws_size,
                              hipStream_t stream) {
    const float* x    = (const float*)d_in[0];
    const int*   edge = (const int*)d_in[1];     // int32 on device (harness converts)
    const float* W1 = (const float*)d_in[2];
    const float* b1 = (const float*)d_in[3];
    const float* W2 = (const float*)d_in[4];
    const float* b2 = (const float*)d_in[5];
    const float* W3 = (const float*)d_in[6];
    const float* b3 = (const float*)d_in[7];
    const float* W4 = (const float*)d_in[8];
    const float* b4 = (const float*)d_in[9];
    const float* W5 = (const float*)d_in[10];
    const float* b5 = (const float*)d_in[11];
    float* out = (float*)d_out;

    const int N = N_NODES, E = N_EDGES;
    const int* src = edge;
    const int* dst = edge + E;

    // float workspace (lifetimes audited; peak 384N floats = 76.8 MB):
    //   agg1 [128N,192N) -> h1 [0,128N) -> agg2 [256N,384N) -> h2 [0,256N)
    //   -> h3 [256N,384N) -> h4 [0,128N)
    float* ws   = (float*)d_ws;
    float* h1   = ws;
    float* agg1 = ws + (size_t)N * 128;
    float* agg2 = ws + (size_t)N * 256;
    float* h2   = ws;
    float* h3   = ws + (size_t)N * 256;
    float* h4   = ws;

    // int workspace after the float region (~4 MB)
    int* ibase   = (int*)(ws + (size_t)N * 384);
    int* deg     = ibase;                  // N (reused as cursor)
    int* row_ptr = ibase + N;              // N+1
    int* colidx  = ibase + 2 * N + 1;      // E
    int* loc     = ibase + 2 * N + 1 + E;  // N
    int* part    = loc + N;                // 64

    const int NB = (N + 1023) / 1024;      // 49 scan blocks

    dim3 blk(256);

    // ---- CSR build (once per call, shared by both GIN layers) ----
    zero_int_kernel<<<64, blk, 0, stream>>>(deg, N);
    hist_kernel<<<2048, blk, 0, stream>>>(dst, deg, E);
    scan_blocks<<<NB, 1024, 0, stream>>>(deg, loc, part, N);
    scan_tops<<<1, 64, 0, stream>>>(part, NB);
    scan_add<<<NB, 1024, 0, stream>>>(loc, part, row_ptr, /*cursor=*/deg, N, NB);
    fill_kernel<<<2048, blk, 0, stream>>>(src, dst, /*cursor=*/deg, colidx, E);

    // ---- layer 1: agg1 = x + gather-sum(x); h1 = relu(agg1 @ W1 + b1) ----
    gin_aggregate<64><<<3125, blk, 0, stream>>>(x, row_ptr, colidx, agg1, N);
    gemm_bias_relu<64><<<dim3(2, 391), blk, 0, stream>>>(agg1, W1, b1, h1, N, 64, 128, 1);

    // ---- layer 2: agg2 = h1 + gather-sum(h1); h2 = relu(agg2 @ W2 + b2) ----
    gin_aggregate<128><<<3125, blk, 0, stream>>>(h1, row_ptr, colidx, agg2, N);
    gemm_bias_relu<128><<<dim3(2, 391), blk, 0, stream>>>(agg2, W2, b2, h2, N, 128, 256, 1);

    // ---- dense head ----
    gemm_bias_relu<64><<<dim3(2, 391), blk, 0, stream>>>(h2, W3, b3, h3, N, 256, 128, 1);
    gemm_bias_relu<64><<<dim3(2, 391), blk, 0, stream>>>(h3, W4, b4, h4, N, 128, 128, 1);
    out_proj_kernel<<<2048, blk, 0, stream>>>(h4, W5, b5, out, N);
}

// Round 13
// 416.952 us; speedup vs baseline: 5.4328x; 1.1055x over previous
//
#include <hip/hip_runtime.h>
#include <cstddef>
#include <cstdint>

#define N_NODES 50000
#define N_EDGES 800000

typedef __bf16 bf16x8 __attribute__((ext_vector_type(8)));
typedef __bf16 bf16x4 __attribute__((ext_vector_type(4)));
typedef float  f32x4  __attribute__((ext_vector_type(4)));

// ---------------------------------------------------------------------------
// CSR build: deg -> multi-block exclusive scan -> slot fill. Indices int32.
// ---------------------------------------------------------------------------
__global__ void zero_int_kernel(int* __restrict__ p, int n) {
    int stride = gridDim.x * blockDim.x;
    for (int i = blockIdx.x * blockDim.x + threadIdx.x; i < n; i += stride) p[i] = 0;
}

__global__ void hist_kernel(const int* __restrict__ dst, int* __restrict__ deg, int E) {
    int stride = gridDim.x * blockDim.x;
    for (int e = blockIdx.x * blockDim.x + threadIdx.x; e < E; e += stride)
        atomicAdd(&deg[dst[e]], 1);
}

__global__ __launch_bounds__(1024)
void scan_blocks(const int* __restrict__ deg, int* __restrict__ loc,
                 int* __restrict__ part, int n) {
    __shared__ int wsum[16];
    const int lane = threadIdx.x & 63;
    const int wid  = threadIdx.x >> 6;
    int i = blockIdx.x * 1024 + threadIdx.x;
    int v = (i < n) ? deg[i] : 0;
    int s = v;
#pragma unroll
    for (int off = 1; off < 64; off <<= 1) {
        int t = __shfl_up(s, off, 64);
        if (lane >= off) s += t;
    }
    if (lane == 63) wsum[wid] = s;
    __syncthreads();
    if (wid == 0) {
        int ws = (lane < 16) ? wsum[lane] : 0;
#pragma unroll
        for (int off = 1; off < 16; off <<= 1) {
            int t = __shfl_up(ws, off, 64);
            if (lane >= off) ws += t;
        }
        if (lane < 16) wsum[lane] = ws;
    }
    __syncthreads();
    int excl = (wid ? wsum[wid - 1] : 0) + s - v;
    if (i < n) loc[i] = excl;
    if (threadIdx.x == 1023) part[blockIdx.x] = wsum[15];
}

__global__ void scan_tops(int* __restrict__ part, int nb) {
    int lane = threadIdx.x;
    int v = (lane < nb) ? part[lane] : 0;
    int s = v;
#pragma unroll
    for (int off = 1; off < 64; off <<= 1) {
        int t = __shfl_up(s, off, 64);
        if (lane >= off) s += t;
    }
    if (lane < nb) part[lane] = s - v;
    if (lane == nb - 1) part[nb] = s;
}

__global__ __launch_bounds__(1024)
void scan_add(const int* __restrict__ loc, const int* __restrict__ part,
              int* __restrict__ row_ptr, int* __restrict__ cursor, int n, int nb) {
    int i = blockIdx.x * 1024 + threadIdx.x;
    if (i < n) {
        int r = loc[i] + part[i >> 10];
        row_ptr[i] = r;
        cursor[i]  = r;
    }
    if (i == 0) row_ptr[n] = part[nb];
}

__global__ void fill_kernel(const int* __restrict__ src, const int* __restrict__ dst,
                            int* __restrict__ cursor, int* __restrict__ col, int E) {
    int stride = gridDim.x * blockDim.x;
    for (int e = blockIdx.x * blockDim.x + threadIdx.x; e < E; e += stride) {
        int p = atomicAdd(&cursor[dst[e]], 1);
        col[p] = src[e];
    }
}

// ---------------------------------------------------------------------------
// GIN aggregation: agg[v] = feat[v] + sum_{u in in-nbrs(v)} feat[u].
// One wave per node; ~5.7 TB/s delivered (measured r5/r8) — near memory floor.
// ---------------------------------------------------------------------------
template<int D>
__global__ __launch_bounds__(256)
void gin_aggregate(const float* __restrict__ feat, const int* __restrict__ row_ptr,
                   const int* __restrict__ col, float* __restrict__ agg, int n) {
    int gwid = (blockIdx.x * blockDim.x + threadIdx.x) >> 6;
    int lane = threadIdx.x & 63;
    int nwav = (gridDim.x * blockDim.x) >> 6;
    for (int v = gwid; v < n; v += nwav) {
        float2 acc;
        if constexpr (D == 128) acc = ((const float2*)(feat + (size_t)v * D))[lane];
        else { acc.x = feat[(size_t)v * D + lane]; acc.y = 0.f; }
        int beg = row_ptr[v], end = row_ptr[v + 1];
        for (int j = beg; j < end; j += 64) {
            int batch = end - j; if (batch > 64) batch = 64;
            int e = (lane < batch) ? col[j + lane] : 0;
            for (int k = 0; k < batch; ++k) {
                int s = __shfl(e, k, 64);
                if constexpr (D == 128) {
                    float2 r = ((const float2*)(feat + (size_t)s * D))[lane];
                    acc.x += r.x; acc.y += r.y;
                } else {
                    acc.x += feat[(size_t)s * D + lane];
                }
            }
        }
        if constexpr (D == 128) ((float2*)(agg + (size_t)v * D))[lane] = acc;
        else agg[(size_t)v * D + lane] = acc.x;
    }
}

// ---------------------------------------------------------------------------
// Weight preprocessing: W[K][N] fp32 -> Wt_hi/Wt_lo [N][K] bf16 (hi = RN(w),
// lo = RN(w - hi)). Tiny (<=65k elems per layer), runs once per call.
// ---------------------------------------------------------------------------
__global__ void wsplit_kernel(const float* __restrict__ W, __bf16* __restrict__ Wth,
                              __bf16* __restrict__ Wtl, int K, int N) {
    int id = blockIdx.x * blockDim.x + threadIdx.x;
    if (id >= K * N) return;
    int k = id / N, n = id % N;
    float w = W[id];
    __bf16 h = (__bf16)w;
    __bf16 l = (__bf16)(w - (float)h);
    Wth[(size_t)n * K + k] = h;
    Wtl[(size_t)n * K + k] = l;
}

// ---------------------------------------------------------------------------
// Split-fp32 MFMA GEMM: C = act(A[M,K] @ W[K,N] + bias) via bf16 hi/lo split:
// a*w ~= ah*wh + ah*wl + al*wh  (3x mfma_f32_16x16x32_bf16, fp32 accum;
// rel err ~2^-16). Block 128x64, 4 waves (2x2), wave tile 64x32 (4x2 frags),
// BK=32. LDS rows padded to 40 bf16 (80 B = odd multiple of 16 B): b128-aligned,
// bank stride 20 -> low conflict. k-mapping (lane>>4)*8+j used identically for
// A and B fragments, so any HW k-permutation cancels; relies only on verified
// facts: A-row/B-col = lane&15, C/D col=lane&15 row=(lane>>4)*4+reg (m89/m91).
// ---------------------------------------------------------------------------
__global__ __launch_bounds__(256)
void gemm_split_bias_relu(const float* __restrict__ A, const __bf16* __restrict__ Wth,
                          const __bf16* __restrict__ Wtl, const float* __restrict__ bias,
                          float* __restrict__ C, int M, int K, int N, int do_relu) {
    __shared__ __align__(16) __bf16 Ah[128][40];
    __shared__ __align__(16) __bf16 Al[128][40];
    __shared__ __align__(16) __bf16 Bh[64][40];
    __shared__ __align__(16) __bf16 Bl[64][40];

    const int tid  = threadIdx.x;
    const int lane = tid & 63;
    const int wave = tid >> 6;
    const int wm   = wave >> 1;            // wave row 0..1 (64 rows each)
    const int wn   = wave & 1;             // wave col 0..1 (32 cols each)
    const int row0 = blockIdx.y * 128;
    const int col0 = blockIdx.x * 64;

    // A staging map: thread -> (row, 16-k half)
    const int srow = tid >> 1;
    const int skh  = (tid & 1) * 16;
    int arow = row0 + srow; if (arow >= M) arow = M - 1;   // clamp; stores guarded
    const float* aptr = A + (size_t)arow * K + skh;

    // B staging map: thread -> (n, 8-k segment); one uint4 (8 bf16) per buffer
    const int bn   = tid >> 2;
    const int bseg = (tid & 3) * 8;
    const __bf16* bhptr = Wth + (size_t)(col0 + bn) * K + bseg;
    const __bf16* blptr = Wtl + (size_t)(col0 + bn) * K + bseg;

    f32x4 acc[4][2];
#pragma unroll
    for (int i = 0; i < 4; ++i)
#pragma unroll
        for (int j = 0; j < 2; ++j) acc[i][j] = (f32x4){0.f, 0.f, 0.f, 0.f};

    const int g8 = (lane >> 4) * 8;
    const int fr = lane & 15;

    for (int k0 = 0; k0 < K; k0 += 32) {
        // ---- stage A (fp32 -> hi/lo bf16) ----
#pragma unroll
        for (int i = 0; i < 4; ++i) {
            float4 v = *(const float4*)(aptr + k0 + i * 4);
            __bf16 h0 = (__bf16)v.x, h1 = (__bf16)v.y, h2 = (__bf16)v.z, h3 = (__bf16)v.w;
            __bf16 l0 = (__bf16)(v.x - (float)h0);
            __bf16 l1 = (__bf16)(v.y - (float)h1);
            __bf16 l2 = (__bf16)(v.z - (float)h2);
            __bf16 l3 = (__bf16)(v.w - (float)h3);
            *(bf16x4*)&Ah[srow][skh + i * 4] = (bf16x4){h0, h1, h2, h3};
            *(bf16x4*)&Al[srow][skh + i * 4] = (bf16x4){l0, l1, l2, l3};
        }
        // ---- stage B (pre-split bf16, straight copy) ----
        {
            uint4 hb = *(const uint4*)(bhptr + k0);
            uint4 lb = *(const uint4*)(blptr + k0);
            *(uint4*)&Bh[bn][bseg] = hb;
            *(uint4*)&Bl[bn][bseg] = lb;
        }
        __syncthreads();

        // ---- fragments + MFMA ----
        bf16x8 bh_[2], bl_[2];
#pragma unroll
        for (int ni = 0; ni < 2; ++ni) {
            int n = wn * 32 + ni * 16 + fr;
            bh_[ni] = *(const bf16x8*)&Bh[n][g8];
            bl_[ni] = *(const bf16x8*)&Bl[n][g8];
        }
#pragma unroll
        for (int mi = 0; mi < 4; ++mi) {
            int r = wm * 64 + mi * 16 + fr;
            bf16x8 ah = *(const bf16x8*)&Ah[r][g8];
            bf16x8 al = *(const bf16x8*)&Al[r][g8];
#pragma unroll
            for (int ni = 0; ni < 2; ++ni) {
                acc[mi][ni] = __builtin_amdgcn_mfma_f32_16x16x32_bf16(ah, bh_[ni], acc[mi][ni], 0, 0, 0);
                acc[mi][ni] = __builtin_amdgcn_mfma_f32_16x16x32_bf16(ah, bl_[ni], acc[mi][ni], 0, 0, 0);
                acc[mi][ni] = __builtin_amdgcn_mfma_f32_16x16x32_bf16(al, bh_[ni], acc[mi][ni], 0, 0, 0);
            }
        }
        __syncthreads();
    }

    // ---- epilogue: bias + relu, guarded stores (lanes 0..15 -> 64B runs) ----
    const int fq = lane >> 4;
#pragma unroll
    for (int ni = 0; ni < 2; ++ni) {
        int colg = col0 + wn * 32 + ni * 16 + fr;
        float bc = bias[colg];
#pragma unroll
        for (int mi = 0; mi < 4; ++mi) {
            int rbase = row0 + wm * 64 + mi * 16 + fq * 4;
#pragma unroll
            for (int j = 0; j < 4; ++j) {
                int r = rbase + j;
                if (r < M) {
                    float t = acc[mi][ni][j] + bc;
                    if (do_relu) t = fmaxf(t, 0.f);
                    C[(size_t)r * N + colg] = t;
                }
            }
        }
    }
}

// ---------------------------------------------------------------------------
// final projection: out[r] = dot(h4[r,:128], w5) + b5, one wave per row
// ---------------------------------------------------------------------------
__global__ void out_proj_kernel(const float* __restrict__ h, const float* __restrict__ w,
                                const float* __restrict__ b, float* __restrict__ out, int M) {
    int lane = threadIdx.x & 63;
    int wave = threadIdx.x >> 6;
    int wpb  = blockDim.x >> 6;
    float w0 = w[lane], w1 = w[64 + lane];
    float bb = b[0];
    for (int row = blockIdx.x * wpb + wave; row < M; row += gridDim.x * wpb) {
        const float* hr = h + (size_t)row * 128;
        float s = hr[lane] * w0 + hr[64 + lane] * w1;
#pragma unroll
        for (int off = 32; off > 0; off >>= 1) s += __shfl_xor(s, off, 64);
        if (lane == 0) out[row] = s + bb;
    }
}

// ---------------------------------------------------------------------------
extern "C" void kernel_launch(void* const* d_in, const int* in_sizes, int n_in,
                              void* d_out, int out_size, void* d_ws, size_t ws_size,
                              hipStream_t stream) {
    const float* x    = (const float*)d_in[0];
    const int*   edge = (const int*)d_in[1];     // int32 on device (harness converts)
    const float* W1 = (const float*)d_in[2];
    const float* b1 = (const float*)d_in[3];
    const float* W2 = (const float*)d_in[4];
    const float* b2 = (const float*)d_in[5];
    const float* W3 = (const float*)d_in[6];
    const float* b3 = (const float*)d_in[7];
    const float* W4 = (const float*)d_in[8];
    const float* b4 = (const float*)d_in[9];
    const float* W5 = (const float*)d_in[10];
    const float* b5 = (const float*)d_in[11];
    float* out = (float*)d_out;

    const int N = N_NODES, E = N_EDGES;
    const int* src = edge;
    const int* dst = edge + E;

    // float workspace (lifetimes audited; peak 384N floats = 76.8 MB):
    //   agg1 [128N,192N) -> h1 [0,128N) -> agg2 [256N,384N) -> h2 [0,256N)
    //   -> h3 [256N,384N) -> h4 [0,128N)
    float* ws   = (float*)d_ws;
    float* h1   = ws;
    float* agg1 = ws + (size_t)N * 128;
    float* agg2 = ws + (size_t)N * 256;
    float* h2   = ws;
    float* h3   = ws + (size_t)N * 256;
    float* h4   = ws;

    // int workspace (~4 MB)
    int* ibase   = (int*)(ws + (size_t)N * 384);
    int* deg     = ibase;                  // N (reused as cursor)
    int* row_ptr = ibase + N;              // N+1
    int* colidx  = ibase + 2 * N + 1;      // E
    int* loc     = ibase + 2 * N + 1 + E;  // N
    int* part    = loc + N;                // 64

    // bf16 split-weight workspace (~360 KB), 16B-aligned
    uintptr_t wp = (uintptr_t)(part + 65);
    wp = (wp + 15) & ~(uintptr_t)15;
    __bf16* wtb  = (__bf16*)wp;
    __bf16* w1h = wtb;            __bf16* w1l = w1h + 64 * 128;
    __bf16* w2h = w1l + 64 * 128; __bf16* w2l = w2h + 128 * 256;
    __bf16* w3h = w2l + 128 * 256; __bf16* w3l = w3h + 256 * 128;
    __bf16* w4h = w3l + 256 * 128; __bf16* w4l = w4h + 128 * 128;

    const int NB = (N + 1023) / 1024;      // 49 scan blocks
    dim3 blk(256);

    // ---- weight preprocessing (independent of CSR) ----
    wsplit_kernel<<<(64 * 128 + 255) / 256, blk, 0, stream>>>(W1, w1h, w1l, 64, 128);
    wsplit_kernel<<<(128 * 256 + 255) / 256, blk, 0, stream>>>(W2, w2h, w2l, 128, 256);
    wsplit_kernel<<<(256 * 128 + 255) / 256, blk, 0, stream>>>(W3, w3h, w3l, 256, 128);
    wsplit_kernel<<<(128 * 128 + 255) / 256, blk, 0, stream>>>(W4, w4h, w4l, 128, 128);

    // ---- CSR build (once per call, shared by both GIN layers) ----
    zero_int_kernel<<<64, blk, 0, stream>>>(deg, N);
    hist_kernel<<<2048, blk, 0, stream>>>(dst, deg, E);
    scan_blocks<<<NB, 1024, 0, stream>>>(deg, loc, part, N);
    scan_tops<<<1, 64, 0, stream>>>(part, NB);
    scan_add<<<NB, 1024, 0, stream>>>(loc, part, row_ptr, /*cursor=*/deg, N, NB);
    fill_kernel<<<2048, blk, 0, stream>>>(src, dst, /*cursor=*/deg, colidx, E);

    // ---- layer 1: agg1 = x + gather-sum(x); h1 = relu(agg1 @ W1 + b1) ----
    gin_aggregate<64><<<3125, blk, 0, stream>>>(x, row_ptr, colidx, agg1, N);
    gemm_split_bias_relu<<<dim3(2, 391), blk, 0, stream>>>(agg1, w1h, w1l, b1, h1, N, 64, 128, 1);

    // ---- layer 2: agg2 = h1 + gather-sum(h1); h2 = relu(agg2 @ W2 + b2) ----
    gin_aggregate<128><<<3125, blk, 0, stream>>>(h1, row_ptr, colidx, agg2, N);
    gemm_split_bias_relu<<<dim3(4, 391), blk, 0, stream>>>(agg2, w2h, w2l, b2, h2, N, 128, 256, 1);

    // ---- dense head ----
    gemm_split_bias_relu<<<dim3(2, 391), blk, 0, stream>>>(h2, w3h, w3l, b3, h3, N, 256, 128, 1);
    gemm_split_bias_relu<<<dim3(2, 391), blk, 0, stream>>>(h3, w4h, w4l, b4, h4, N, 128, 128, 1);
    out_proj_kernel<<<2048, blk, 0, stream>>>(h4, W5, b5, out, N);
}